// Round 1
// baseline (59.357 us; speedup 1.0000x reference)
//
#include <hip/hip_runtime.h>
#include <math.h>

#define NE 4096
#define NROWS_STATE 160   // 5 * 32 layers

// ws layout (floats)
#define WS_XK   0
#define WS_XV   (NE)
#define WS_XR   (2*NE)
#define WS_KK   (3*NE)
#define WS_VV   (4*NE)
#define WS_RR   (5*NE)
#define WS_RWKV (6*NE)

__device__ __forceinline__ float block_reduce_sum(float v, float* sm) {
    // wave (64-lane) reduce
    #pragma unroll
    for (int off = 32; off > 0; off >>= 1)
        v += __shfl_down(v, off, 64);
    int lane = threadIdx.x & 63;
    int wid  = threadIdx.x >> 6;
    if (lane == 0) sm[wid] = v;
    __syncthreads();
    int nw = blockDim.x >> 6;
    if (wid == 0) {
        v = (lane < nw) ? sm[lane] : 0.0f;
        #pragma unroll
        for (int off = 32; off > 0; off >>= 1)
            v += __shfl_down(v, off, 64);
    }
    return v;  // valid in thread 0
}

// ---------------- kernel 1: copy full state into d_out ----------------
__global__ void k_copy_state(const float4* __restrict__ src, float4* __restrict__ dst, int n4) {
    int i = blockIdx.x * blockDim.x + threadIdx.x;
    if (i < n4) dst[i] = src[i];
}

// ---------------- kernel 2: layernorm + time-mix ----------------
// one block, 512 threads, each handles 8 elements
__global__ void __launch_bounds__(512)
k_ln_mix(const float* __restrict__ in, const float* __restrict__ state,
         const float* __restrict__ tmk, const float* __restrict__ tmv,
         const float* __restrict__ tmr, const float* __restrict__ lnw,
         const float* __restrict__ lnb, const int* __restrict__ layer,
         float* __restrict__ out_state, float* __restrict__ ws) {
    __shared__ float sm1[8];
    __shared__ float sm2[8];
    __shared__ float s_mu, s_rstd;
    int t = threadIdx.x;

    float4 v0 = ((const float4*)in)[t * 2 + 0];
    float4 v1 = ((const float4*)in)[t * 2 + 1];
    float sum   = v0.x + v0.y + v0.z + v0.w + v1.x + v1.y + v1.z + v1.w;
    float sumsq = v0.x*v0.x + v0.y*v0.y + v0.z*v0.z + v0.w*v0.w
                + v1.x*v1.x + v1.y*v1.y + v1.z*v1.z + v1.w*v1.w;

    // two reductions (separate LDS arrays so one __syncthreads suffices per phase)
    float tot  = block_reduce_sum(sum, sm1);
    __syncthreads();
    float tot2 = block_reduce_sum(sumsq, sm2);
    if (t == 0) {
        float mu  = tot * (1.0f / NE);
        float var = tot2 * (1.0f / NE) - mu * mu;
        s_mu   = mu;
        s_rstd = rsqrtf(var + 1e-5f);
    }
    __syncthreads();

    float mu = s_mu, rstd = s_rstd;
    int li = layer[0];
    const float* prev_row = state + (size_t)(5 * li + 1) * NE;
    float* x_row = out_state + (size_t)(5 * li + 1) * NE;

    #pragma unroll
    for (int j = 0; j < 8; ++j) {
        int idx = t * 8 + j;
        float xin  = in[idx];
        float x    = (xin - mu) * rstd * lnw[idx] + lnb[idx];
        float prev = prev_row[idx];
        float mk = tmk[idx], mv = tmv[idx], mr = tmr[idx];
        ws[WS_XK + idx] = x * mk + prev * (1.0f - mk);
        ws[WS_XV + idx] = x * mv + prev * (1.0f - mv);
        ws[WS_XR + idx] = x * mr + prev * (1.0f - mr);
        x_row[idx] = x;
    }
}

// ---------------- kernel 3: fused 3-matrix matvec ----------------
// grid = 3*4096 blocks, 256 threads; block b computes row (b&4095) of matrix (b>>12)
__global__ void __launch_bounds__(256)
k_matvec3(const float* __restrict__ kw, const float* __restrict__ vw,
          const float* __restrict__ rw, const float* __restrict__ ws_in,
          float* __restrict__ ws_out) {
    int bid = blockIdx.x;
    int m   = bid >> 12;
    int row = bid & (NE - 1);
    const float* W = (m == 0) ? kw : (m == 1) ? vw : rw;
    const float4* Wr = (const float4*)(W + (size_t)row * NE);
    const float4* xv = (const float4*)(ws_in + m * NE);

    int t = threadIdx.x;
    float acc = 0.0f;
    #pragma unroll
    for (int j = 0; j < 4; ++j) {           // 4 passes of 256 threads * float4 = 4096 B each
        float4 w4 = Wr[j * 256 + t];
        float4 x4 = xv[j * 256 + t];
        acc += w4.x * x4.x + w4.y * x4.y + w4.z * x4.z + w4.w * x4.w;
    }
    __shared__ float sm[4];
    float r = block_reduce_sum(acc, sm);
    if (t == 0) {
        if (m == 2) r = 1.0f / (1.0f + expf(-r));   // sigmoid for rw path
        ws_out[m * NE + row] = r;
    }
}

// ---------------- kernel 4: WKV elementwise + state update ----------------
__global__ void k_wkv(const float* __restrict__ state, const float* __restrict__ tf,
                      const float* __restrict__ td, const int* __restrict__ layer,
                      const float* __restrict__ ws, float* __restrict__ out_state,
                      float* __restrict__ rwkv) {
    int idx = blockIdx.x * blockDim.x + threadIdx.x;
    if (idx >= NE) return;
    int li = layer[0];
    float kk = ws[WS_KK + idx];
    float vv = ws[WS_VV + idx];
    float r  = ws[WS_RR + idx];
    float aa = state[(size_t)(5 * li + 2) * NE + idx];
    float bb = state[(size_t)(5 * li + 3) * NE + idx];
    float pp = state[(size_t)(5 * li + 4) * NE + idx];

    float ww = tf[idx] + kk;
    float p  = fmaxf(pp, ww);
    float e1 = expf(pp - p);
    float e2 = expf(ww - p);
    float a  = e1 * aa + e2 * vv;
    float b  = e1 * bb + e2;

    float ww2 = pp + td[idx];
    float p2  = fmaxf(ww2, kk);
    float e1s = expf(ww2 - p2);
    float e2s = expf(kk - p2);
    out_state[(size_t)(5 * li + 2) * NE + idx] = e1s * aa + e2s * vv;
    out_state[(size_t)(5 * li + 3) * NE + idx] = e1s * bb + e2s;
    out_state[(size_t)(5 * li + 4) * NE + idx] = p2;

    rwkv[idx] = r * (a / b);
}

// ---------------- kernel 5: output matvec ----------------
__global__ void __launch_bounds__(256)
k_matvec_ow(const float* __restrict__ ow, const float* __restrict__ rwkv,
            float* __restrict__ out) {
    int row = blockIdx.x;
    const float4* Wr = (const float4*)(ow + (size_t)row * NE);
    const float4* xv = (const float4*)rwkv;
    int t = threadIdx.x;
    float acc = 0.0f;
    #pragma unroll
    for (int j = 0; j < 4; ++j) {
        float4 w4 = Wr[j * 256 + t];
        float4 x4 = xv[j * 256 + t];
        acc += w4.x * x4.x + w4.y * x4.y + w4.z * x4.z + w4.w * x4.w;
    }
    __shared__ float sm[4];
    float r = block_reduce_sum(acc, sm);
    if (t == 0) out[row] = r;
}

extern "C" void kernel_launch(void* const* d_in, const int* in_sizes, int n_in,
                              void* d_out, int out_size, void* d_ws, size_t ws_size,
                              hipStream_t stream) {
    const float* input = (const float*)d_in[0];
    const float* state = (const float*)d_in[1];
    const float* tmk   = (const float*)d_in[2];
    const float* tmv   = (const float*)d_in[3];
    const float* tmr   = (const float*)d_in[4];
    const float* tf    = (const float*)d_in[5];
    const float* td    = (const float*)d_in[6];
    const float* kw    = (const float*)d_in[7];
    const float* vw    = (const float*)d_in[8];
    const float* rw    = (const float*)d_in[9];
    const float* ow    = (const float*)d_in[10];
    const float* lnw   = (const float*)d_in[11];
    const float* lnb   = (const float*)d_in[12];
    const int*   layer = (const int*)d_in[13];

    float* out_state = (float*)d_out;                       // 160*4096 floats
    float* out_vec   = (float*)d_out + (size_t)NROWS_STATE * NE;  // 4096 floats
    float* ws        = (float*)d_ws;

    // 1. copy full old state into output (rows 5i+1..5i+4 overwritten below)
    {
        int n4 = NROWS_STATE * NE / 4;
        k_copy_state<<<(n4 + 255) / 256, 256, 0, stream>>>(
            (const float4*)state, (float4*)out_state, n4);
    }
    // 2. layernorm + time-mix blends
    k_ln_mix<<<1, 512, 0, stream>>>(input, state, tmk, tmv, tmr, lnw, lnb,
                                    layer, out_state, ws);
    // 3. kk / vv / r matvecs
    k_matvec3<<<3 * NE, 256, 0, stream>>>(kw, vw, rw, ws, ws + WS_KK);
    // 4. WKV recurrence
    k_wkv<<<NE / 256, 256, 0, stream>>>(state, tf, td, layer, ws, out_state,
                                        ws + WS_RWKV);
    // 5. out = ow @ (r * wkv)
    k_matvec_ow<<<NE, 256, 0, stream>>>(ow, ws + WS_RWKV, out_vec);
}

// Round 2
// 58.462 us; speedup vs baseline: 1.0153x; 1.0153x over previous
//
#include <hip/hip_runtime.h>
#include <math.h>

#define NE 4096
#define NROWS_STATE 160   // 5 * 32 layers

// ws layout (floats)
#define WS_XK   0
#define WS_XV   (NE)
#define WS_XR   (2*NE)
#define WS_KK   (3*NE)
#define WS_VV   (4*NE)
#define WS_RR   (5*NE)
#define WS_RWKV (6*NE)

__device__ __forceinline__ float wave_reduce_sum(float v) {
    #pragma unroll
    for (int off = 32; off > 0; off >>= 1)
        v += __shfl_down(v, off, 64);
    return v;  // valid in lane 0
}

// ---------------- kernel 1: state copy (skipping written rows) + LN + time-mix ----------------
// block 0: LN + mix (256 threads, 16 elems each)
// blocks 1..640: copy state float4s, skipping rows 5i+1..5i+4
__global__ void __launch_bounds__(256)
k_copy_ln_mix(const float* __restrict__ in, const float* __restrict__ state,
              const float* __restrict__ tmk, const float* __restrict__ tmv,
              const float* __restrict__ tmr, const float* __restrict__ lnw,
              const float* __restrict__ lnb, const int* __restrict__ layer,
              float* __restrict__ out_state, float* __restrict__ ws) {
    int li = layer[0];
    if (blockIdx.x != 0) {
        // ---- copy path ----
        int i4 = (blockIdx.x - 1) * 256 + threadIdx.x;   // float4 index, 1024 per row
        int row = i4 >> 10;
        if (row < 5 * li + 1 || row > 5 * li + 4) {
            ((float4*)out_state)[i4] = ((const float4*)state)[i4];
        }
        return;
    }
    // ---- LN + mix path (block 0) ----
    __shared__ float sm1[4];
    __shared__ float sm2[4];
    __shared__ float s_mu, s_rstd;
    int t = threadIdx.x;
    int lane = t & 63, wid = t >> 6;

    float4 v[4];
    float sum = 0.0f, sumsq = 0.0f;
    #pragma unroll
    for (int j = 0; j < 4; ++j) {
        v[j] = ((const float4*)in)[t * 4 + j];
        sum   += v[j].x + v[j].y + v[j].z + v[j].w;
        sumsq += v[j].x*v[j].x + v[j].y*v[j].y + v[j].z*v[j].z + v[j].w*v[j].w;
    }
    float s1 = wave_reduce_sum(sum);
    float s2 = wave_reduce_sum(sumsq);
    if (lane == 0) { sm1[wid] = s1; sm2[wid] = s2; }
    __syncthreads();
    if (t == 0) {
        float tot = sm1[0] + sm1[1] + sm1[2] + sm1[3];
        float tot2 = sm2[0] + sm2[1] + sm2[2] + sm2[3];
        float mu  = tot * (1.0f / NE);
        float var = tot2 * (1.0f / NE) - mu * mu;
        s_mu = mu;
        s_rstd = rsqrtf(var + 1e-5f);
    }
    __syncthreads();
    float mu = s_mu, rstd = s_rstd;

    const float* prev_row = state + (size_t)(5 * li + 1) * NE;
    float* x_row = out_state + (size_t)(5 * li + 1) * NE;

    #pragma unroll
    for (int j = 0; j < 4; ++j) {
        #pragma unroll
        for (int c = 0; c < 4; ++c) {
            int idx = t * 16 + j * 4 + c;
            float xin = (c == 0) ? v[j].x : (c == 1) ? v[j].y : (c == 2) ? v[j].z : v[j].w;
            float x    = (xin - mu) * rstd * lnw[idx] + lnb[idx];
            float prev = prev_row[idx];
            float mk = tmk[idx], mv = tmv[idx], mr = tmr[idx];
            ws[WS_XK + idx] = x * mk + prev * (1.0f - mk);
            ws[WS_XV + idx] = x * mv + prev * (1.0f - mv);
            ws[WS_XR + idx] = x * mr + prev * (1.0f - mr);
            x_row[idx] = x;
        }
    }
}

// ---------------- kernel 2: fused 3-matrix matvec, one wave per row ----------------
// grid = 3*4096/4 = 3072 blocks of 256 (4 waves); wave g handles row (g&4095) of matrix (g>>12)
__global__ void __launch_bounds__(256)
k_matvec3(const float* __restrict__ kw, const float* __restrict__ vw,
          const float* __restrict__ rw, const float* __restrict__ ws_in,
          float* __restrict__ ws_out) {
    int lane = threadIdx.x & 63;
    int gw   = blockIdx.x * 4 + (threadIdx.x >> 6);
    int m    = gw >> 12;
    int row  = gw & (NE - 1);
    const float* W = (m == 0) ? kw : (m == 1) ? vw : rw;
    const float4* Wr = (const float4*)(W + (size_t)row * NE);
    const float4* xv = (const float4*)(ws_in + m * NE);

    float acc0 = 0.0f, acc1 = 0.0f, acc2 = 0.0f, acc3 = 0.0f;
    #pragma unroll
    for (int j = 0; j < 4; ++j) {
        float4 w0 = Wr[(j*4+0) * 64 + lane];
        float4 w1 = Wr[(j*4+1) * 64 + lane];
        float4 w2 = Wr[(j*4+2) * 64 + lane];
        float4 w3 = Wr[(j*4+3) * 64 + lane];
        float4 x0 = xv[(j*4+0) * 64 + lane];
        float4 x1 = xv[(j*4+1) * 64 + lane];
        float4 x2 = xv[(j*4+2) * 64 + lane];
        float4 x3 = xv[(j*4+3) * 64 + lane];
        acc0 += w0.x*x0.x + w0.y*x0.y + w0.z*x0.z + w0.w*x0.w;
        acc1 += w1.x*x1.x + w1.y*x1.y + w1.z*x1.z + w1.w*x1.w;
        acc2 += w2.x*x2.x + w2.y*x2.y + w2.z*x2.z + w2.w*x2.w;
        acc3 += w3.x*x3.x + w3.y*x3.y + w3.z*x3.z + w3.w*x3.w;
    }
    float a = (acc0 + acc1) + (acc2 + acc3);
    a = wave_reduce_sum(a);
    if (lane == 0) {
        if (m == 2) a = 1.0f / (1.0f + expf(-a));   // sigmoid on r path
        ws_out[m * NE + row] = a;
    }
}

// ---------------- kernel 3: WKV elementwise + state update ----------------
__global__ void k_wkv(const float* __restrict__ state, const float* __restrict__ tf,
                      const float* __restrict__ td, const int* __restrict__ layer,
                      const float* __restrict__ ws, float* __restrict__ out_state,
                      float* __restrict__ rwkv) {
    int idx = blockIdx.x * blockDim.x + threadIdx.x;
    if (idx >= NE) return;
    int li = layer[0];
    float kk = ws[WS_KK + idx];
    float vv = ws[WS_VV + idx];
    float r  = ws[WS_RR + idx];
    float aa = state[(size_t)(5 * li + 2) * NE + idx];
    float bb = state[(size_t)(5 * li + 3) * NE + idx];
    float pp = state[(size_t)(5 * li + 4) * NE + idx];

    float ww = tf[idx] + kk;
    float p  = fmaxf(pp, ww);
    float e1 = expf(pp - p);
    float e2 = expf(ww - p);
    float a  = e1 * aa + e2 * vv;
    float b  = e1 * bb + e2;

    float ww2 = pp + td[idx];
    float p2  = fmaxf(ww2, kk);
    float e1s = expf(ww2 - p2);
    float e2s = expf(kk - p2);
    out_state[(size_t)(5 * li + 2) * NE + idx] = e1s * aa + e2s * vv;
    out_state[(size_t)(5 * li + 3) * NE + idx] = e1s * bb + e2s;
    out_state[(size_t)(5 * li + 4) * NE + idx] = p2;

    rwkv[idx] = r * (a / b);
}

// ---------------- kernel 4: output matvec, one wave per row ----------------
__global__ void __launch_bounds__(256)
k_matvec_ow(const float* __restrict__ ow, const float* __restrict__ rwkv,
            float* __restrict__ out) {
    int lane = threadIdx.x & 63;
    int row  = blockIdx.x * 4 + (threadIdx.x >> 6);
    const float4* Wr = (const float4*)(ow + (size_t)row * NE);
    const float4* xv = (const float4*)rwkv;

    float acc0 = 0.0f, acc1 = 0.0f, acc2 = 0.0f, acc3 = 0.0f;
    #pragma unroll
    for (int j = 0; j < 4; ++j) {
        float4 w0 = Wr[(j*4+0) * 64 + lane];
        float4 w1 = Wr[(j*4+1) * 64 + lane];
        float4 w2 = Wr[(j*4+2) * 64 + lane];
        float4 w3 = Wr[(j*4+3) * 64 + lane];
        float4 x0 = xv[(j*4+0) * 64 + lane];
        float4 x1 = xv[(j*4+1) * 64 + lane];
        float4 x2 = xv[(j*4+2) * 64 + lane];
        float4 x3 = xv[(j*4+3) * 64 + lane];
        acc0 += w0.x*x0.x + w0.y*x0.y + w0.z*x0.z + w0.w*x0.w;
        acc1 += w1.x*x1.x + w1.y*x1.y + w1.z*x1.z + w1.w*x1.w;
        acc2 += w2.x*x2.x + w2.y*x2.y + w2.z*x2.z + w2.w*x2.w;
        acc3 += w3.x*x3.x + w3.y*x3.y + w3.z*x3.z + w3.w*x3.w;
    }
    float a = (acc0 + acc1) + (acc2 + acc3);
    a = wave_reduce_sum(a);
    if (lane == 0) out[row] = a;
}

extern "C" void kernel_launch(void* const* d_in, const int* in_sizes, int n_in,
                              void* d_out, int out_size, void* d_ws, size_t ws_size,
                              hipStream_t stream) {
    const float* input = (const float*)d_in[0];
    const float* state = (const float*)d_in[1];
    const float* tmk   = (const float*)d_in[2];
    const float* tmv   = (const float*)d_in[3];
    const float* tmr   = (const float*)d_in[4];
    const float* tf    = (const float*)d_in[5];
    const float* td    = (const float*)d_in[6];
    const float* kw    = (const float*)d_in[7];
    const float* vw    = (const float*)d_in[8];
    const float* rw    = (const float*)d_in[9];
    const float* ow    = (const float*)d_in[10];
    const float* lnw   = (const float*)d_in[11];
    const float* lnb   = (const float*)d_in[12];
    const int*   layer = (const int*)d_in[13];

    float* out_state = (float*)d_out;                            // 160*4096 floats
    float* out_vec   = (float*)d_out + (size_t)NROWS_STATE * NE; // 4096 floats
    float* ws        = (float*)d_ws;

    // 1. state copy (skips rows written later) + layernorm + time-mix. 1 LN block + 640 copy blocks
    k_copy_ln_mix<<<641, 256, 0, stream>>>(input, state, tmk, tmv, tmr, lnw, lnb,
                                           layer, out_state, ws);
    // 2. kk / vv / r matvecs — one wave per row
    k_matvec3<<<3 * NE / 4, 256, 0, stream>>>(kw, vw, rw, ws, ws + WS_KK);
    // 3. WKV recurrence
    k_wkv<<<NE / 256, 256, 0, stream>>>(state, tf, td, layer, ws, out_state,
                                        ws + WS_RWKV);
    // 4. out = ow @ (r * wkv) — one wave per row
    k_matvec_ow<<<NE / 4, 256, 0, stream>>>(ow, ws + WS_RWKV, out_vec);
}

// Round 3
// 57.294 us; speedup vs baseline: 1.0360x; 1.0204x over previous
//
#include <hip/hip_runtime.h>
#include <math.h>

#define NE 4096
#define NROWS_STATE 160   // 5 * 32 layers

// ws layout (floats)
#define WS_XK   0
#define WS_XV   (NE)
#define WS_XR   (2*NE)
#define WS_KK   (3*NE)
#define WS_VV   (4*NE)
#define WS_RR   (5*NE)
#define WS_RWKV (6*NE)

__device__ __forceinline__ float wave_reduce_sum(float v) {
    #pragma unroll
    for (int off = 32; off > 0; off >>= 1)
        v += __shfl_down(v, off, 64);
    return v;  // valid in lane 0
}

// ---------------- kernel 1: state copy (skipping written rows) + LN + time-mix ----------------
__global__ void __launch_bounds__(256)
k_copy_ln_mix(const float* __restrict__ in, const float* __restrict__ state,
              const float* __restrict__ tmk, const float* __restrict__ tmv,
              const float* __restrict__ tmr, const float* __restrict__ lnw,
              const float* __restrict__ lnb, const int* __restrict__ layer,
              float* __restrict__ out_state, float* __restrict__ ws) {
    int li = layer[0];
    if (blockIdx.x != 0) {
        int i4 = (blockIdx.x - 1) * 256 + threadIdx.x;   // float4 index, 1024 per row
        int row = i4 >> 10;
        if (row < 5 * li + 1 || row > 5 * li + 4) {
            ((float4*)out_state)[i4] = ((const float4*)state)[i4];
        }
        return;
    }
    __shared__ float sm1[4];
    __shared__ float sm2[4];
    __shared__ float s_mu, s_rstd;
    int t = threadIdx.x;
    int lane = t & 63, wid = t >> 6;

    float4 v[4];
    float sum = 0.0f, sumsq = 0.0f;
    #pragma unroll
    for (int j = 0; j < 4; ++j) {
        v[j] = ((const float4*)in)[t * 4 + j];
        sum   += v[j].x + v[j].y + v[j].z + v[j].w;
        sumsq += v[j].x*v[j].x + v[j].y*v[j].y + v[j].z*v[j].z + v[j].w*v[j].w;
    }
    float s1 = wave_reduce_sum(sum);
    float s2 = wave_reduce_sum(sumsq);
    if (lane == 0) { sm1[wid] = s1; sm2[wid] = s2; }
    __syncthreads();
    if (t == 0) {
        float tot = sm1[0] + sm1[1] + sm1[2] + sm1[3];
        float tot2 = sm2[0] + sm2[1] + sm2[2] + sm2[3];
        float mu  = tot * (1.0f / NE);
        float var = tot2 * (1.0f / NE) - mu * mu;
        s_mu = mu;
        s_rstd = rsqrtf(var + 1e-5f);
    }
    __syncthreads();
    float mu = s_mu, rstd = s_rstd;

    const float* prev_row = state + (size_t)(5 * li + 1) * NE;
    float* x_row = out_state + (size_t)(5 * li + 1) * NE;

    #pragma unroll
    for (int j = 0; j < 4; ++j) {
        #pragma unroll
        for (int c = 0; c < 4; ++c) {
            int idx = t * 16 + j * 4 + c;
            float xin = (c == 0) ? v[j].x : (c == 1) ? v[j].y : (c == 2) ? v[j].z : v[j].w;
            float x    = (xin - mu) * rstd * lnw[idx] + lnb[idx];
            float prev = prev_row[idx];
            float mk = tmk[idx], mv = tmv[idx], mr = tmr[idx];
            ws[WS_XK + idx] = x * mk + prev * (1.0f - mk);
            ws[WS_XV + idx] = x * mv + prev * (1.0f - mv);
            ws[WS_XR + idx] = x * mr + prev * (1.0f - mr);
            x_row[idx] = x;
        }
    }
}

// ---------------- kernel 2: fused 3-matrix matvec ----------------
// One wave per row; x staged in LDS (lgkmcnt path); entire 16KB W-row loaded
// into 16 statically-indexed float4 regs so all 16 global loads stay in flight.
// grid = 3*4096/4 blocks of 256 (4 waves). 4096%4==0 so a block never straddles matrices.
__global__ void __launch_bounds__(256)
k_matvec3(const float* __restrict__ kw, const float* __restrict__ vw,
          const float* __restrict__ rw, const float* __restrict__ ws_in,
          float* __restrict__ ws_out) {
    __shared__ float4 sx[NE / 4];           // 16 KB: x for this block's matrix
    int t    = threadIdx.x;
    int lane = t & 63;
    int gw   = blockIdx.x * 4 + (t >> 6);
    int m    = gw >> 12;
    int row  = gw & (NE - 1);
    const float* W = (m == 0) ? kw : (m == 1) ? vw : rw;
    const float4* xg = (const float4*)(ws_in + m * NE);
    #pragma unroll
    for (int j = 0; j < 4; ++j) sx[t + j * 256] = xg[t + j * 256];
    __syncthreads();

    const float4* Wr = (const float4*)(W + (size_t)row * NE);
    float4 w[16];
    #pragma unroll
    for (int i = 0; i < 16; ++i) w[i] = Wr[i * 64 + lane];

    float acc0 = 0.0f, acc1 = 0.0f, acc2 = 0.0f, acc3 = 0.0f;
    #pragma unroll
    for (int i = 0; i < 16; i += 4) {
        float4 x0 = sx[(i + 0) * 64 + lane];
        float4 x1 = sx[(i + 1) * 64 + lane];
        float4 x2 = sx[(i + 2) * 64 + lane];
        float4 x3 = sx[(i + 3) * 64 + lane];
        acc0 += w[i+0].x*x0.x + w[i+0].y*x0.y + w[i+0].z*x0.z + w[i+0].w*x0.w;
        acc1 += w[i+1].x*x1.x + w[i+1].y*x1.y + w[i+1].z*x1.z + w[i+1].w*x1.w;
        acc2 += w[i+2].x*x2.x + w[i+2].y*x2.y + w[i+2].z*x2.z + w[i+2].w*x2.w;
        acc3 += w[i+3].x*x3.x + w[i+3].y*x3.y + w[i+3].z*x3.z + w[i+3].w*x3.w;
    }
    float a = (acc0 + acc1) + (acc2 + acc3);
    a = wave_reduce_sum(a);
    if (lane == 0) {
        if (m == 2) a = 1.0f / (1.0f + expf(-a));   // sigmoid on r path
        ws_out[m * NE + row] = a;
    }
}

// ---------------- kernel 3: WKV elementwise + state update ----------------
__global__ void k_wkv(const float* __restrict__ state, const float* __restrict__ tf,
                      const float* __restrict__ td, const int* __restrict__ layer,
                      const float* __restrict__ ws, float* __restrict__ out_state,
                      float* __restrict__ rwkv) {
    int idx = blockIdx.x * blockDim.x + threadIdx.x;
    if (idx >= NE) return;
    int li = layer[0];
    float kk = ws[WS_KK + idx];
    float vv = ws[WS_VV + idx];
    float r  = ws[WS_RR + idx];
    float aa = state[(size_t)(5 * li + 2) * NE + idx];
    float bb = state[(size_t)(5 * li + 3) * NE + idx];
    float pp = state[(size_t)(5 * li + 4) * NE + idx];

    float ww = tf[idx] + kk;
    float p  = fmaxf(pp, ww);
    float e1 = expf(pp - p);
    float e2 = expf(ww - p);
    float a  = e1 * aa + e2 * vv;
    float b  = e1 * bb + e2;

    float ww2 = pp + td[idx];
    float p2  = fmaxf(ww2, kk);
    float e1s = expf(ww2 - p2);
    float e2s = expf(kk - p2);
    out_state[(size_t)(5 * li + 2) * NE + idx] = e1s * aa + e2s * vv;
    out_state[(size_t)(5 * li + 3) * NE + idx] = e1s * bb + e2s;
    out_state[(size_t)(5 * li + 4) * NE + idx] = p2;

    rwkv[idx] = r * (a / b);
}

// ---------------- kernel 4: output matvec (same MLP structure) ----------------
__global__ void __launch_bounds__(256)
k_matvec_ow(const float* __restrict__ ow, const float* __restrict__ rwkv,
            float* __restrict__ out) {
    __shared__ float4 sx[NE / 4];           // 16 KB: rwkv vector
    int t    = threadIdx.x;
    int lane = t & 63;
    int row  = blockIdx.x * 4 + (t >> 6);
    const float4* xg = (const float4*)rwkv;
    #pragma unroll
    for (int j = 0; j < 4; ++j) sx[t + j * 256] = xg[t + j * 256];
    __syncthreads();

    const float4* Wr = (const float4*)(ow + (size_t)row * NE);
    float4 w[16];
    #pragma unroll
    for (int i = 0; i < 16; ++i) w[i] = Wr[i * 64 + lane];

    float acc0 = 0.0f, acc1 = 0.0f, acc2 = 0.0f, acc3 = 0.0f;
    #pragma unroll
    for (int i = 0; i < 16; i += 4) {
        float4 x0 = sx[(i + 0) * 64 + lane];
        float4 x1 = sx[(i + 1) * 64 + lane];
        float4 x2 = sx[(i + 2) * 64 + lane];
        float4 x3 = sx[(i + 3) * 64 + lane];
        acc0 += w[i+0].x*x0.x + w[i+0].y*x0.y + w[i+0].z*x0.z + w[i+0].w*x0.w;
        acc1 += w[i+1].x*x1.x + w[i+1].y*x1.y + w[i+1].z*x1.z + w[i+1].w*x1.w;
        acc2 += w[i+2].x*x2.x + w[i+2].y*x2.y + w[i+2].z*x2.z + w[i+2].w*x2.w;
        acc3 += w[i+3].x*x3.x + w[i+3].y*x3.y + w[i+3].z*x3.z + w[i+3].w*x3.w;
    }
    float a = (acc0 + acc1) + (acc2 + acc3);
    a = wave_reduce_sum(a);
    if (lane == 0) out[row] = a;
}

extern "C" void kernel_launch(void* const* d_in, const int* in_sizes, int n_in,
                              void* d_out, int out_size, void* d_ws, size_t ws_size,
                              hipStream_t stream) {
    const float* input = (const float*)d_in[0];
    const float* state = (const float*)d_in[1];
    const float* tmk   = (const float*)d_in[2];
    const float* tmv   = (const float*)d_in[3];
    const float* tmr   = (const float*)d_in[4];
    const float* tf    = (const float*)d_in[5];
    const float* td    = (const float*)d_in[6];
    const float* kw    = (const float*)d_in[7];
    const float* vw    = (const float*)d_in[8];
    const float* rw    = (const float*)d_in[9];
    const float* ow    = (const float*)d_in[10];
    const float* lnw   = (const float*)d_in[11];
    const float* lnb   = (const float*)d_in[12];
    const int*   layer = (const int*)d_in[13];

    float* out_state = (float*)d_out;                            // 160*4096 floats
    float* out_vec   = (float*)d_out + (size_t)NROWS_STATE * NE; // 4096 floats
    float* ws        = (float*)d_ws;

    // 1. state copy (skips rows written later) + layernorm + time-mix
    k_copy_ln_mix<<<641, 256, 0, stream>>>(input, state, tmk, tmv, tmr, lnw, lnb,
                                           layer, out_state, ws);
    // 2. kk / vv / r matvecs — one wave per row, 16 W-loads in flight
    k_matvec3<<<3 * NE / 4, 256, 0, stream>>>(kw, vw, rw, ws, ws + WS_KK);
    // 3. WKV recurrence
    k_wkv<<<NE / 256, 256, 0, stream>>>(state, tf, td, layer, ws, out_state,
                                        ws + WS_RWKV);
    // 4. out = ow @ (r * wkv)
    k_matvec_ow<<<NE / 4, 256, 0, stream>>>(ow, ws + WS_RWKV, out_vec);
}